// Round 5
// baseline (101.088 us; speedup 1.0000x reference)
//
#include <hip/hip_runtime.h>
#include <float.h>
#include <math.h>

#define T_DIM 2048
#define C_DIM 512
#define QKV_LD 1536
#define NBLK 512

typedef float f32x4 __attribute__((ext_vector_type(4)));
typedef short s16x8 __attribute__((ext_vector_type(8)));
typedef unsigned u32x4 __attribute__((ext_vector_type(4)));

__device__ __forceinline__ unsigned short f2bf(float f) {
  unsigned u = __float_as_uint(f);
  return (unsigned short)((u + 0x7fffu + ((u >> 16) & 1u)) >> 16);
}

// async 16B global->LDS; LDS dest must be wave-uniform base + lane*16.
__device__ __forceinline__ void load16_to_lds(const void* g, void* l) {
  __builtin_amdgcn_global_load_lds(
      (const __attribute__((address_space(1))) unsigned int*)g,
      (__attribute__((address_space(3))) unsigned int*)(unsigned int)(unsigned long long)l,
      16, 0, 0);
}

// ---------------------------------------------------------------------------
// Fused bf16 MFMA GEMM: C = cast(A) * cast(B)^T where B is consumed DIRECTLY
// from the f32 weight matrix W[K][N] (transpose happens in staging).
// R5: prep_kernel deleted.  A path: A_CAST ? (f32 x, reg-cast, stride-40 LDS)
//                                  : (bf16, global_load_lds, stride-32 LDS).
// B path: per thread one tile-col n + KPT k-pairs; 2*KPT coalesced scalar
// loads (lanes span consecutive n -> 256B/instr), pack bf16 pairs, 16B-
// aligned contiguous writes into lB[n][k] (stride 40 -> banks cycle 8 vals).
// K-loop: R4's 1-barrier double-buffer; loads for t+2 issued at t, LDS
// writes for t+1 right after the barrier at t.
// Numerics bit-identical to the old prep+gemm pipeline (same f2bf inputs).
// ---------------------------------------------------------------------------
template <int BM, int BN, int KDIM, bool A_CAST, bool OUT16>
__device__ __forceinline__ void gemm_body(const void* __restrict__ Ap,
                                          const float* __restrict__ Bw,
                                          void* __restrict__ Cp,
                                          int N, int ldb, int tilesX,
                                          unsigned short* lA, unsigned short* lB,
                                          int tid, int bid) {
  constexpr int BK = 32;
  constexpr int LDA = A_CAST ? 40 : 32;   // padded only on the reg-staged path
  constexpr int LDB = 40;
  constexpr int ASZ = BM * LDA, BSZ = BN * LDB;
  constexpr int KPT = BN * 16 / 256;      // k-pairs per thread in B staging
  constexpr int BM2 = BM / 2, BN2 = BN / 2;
  constexpr int MT = BM2 / 16, NT = BN2 / 16;
  constexpr int nt = KDIM / BK;
  static_assert(!A_CAST || BM == 128, "A cast staging assumes BM=128");

  const int lane = tid & 63, w = tid >> 6, wr = w >> 1, wc = w & 1;
  const int fm = lane & 15, q8 = (lane >> 4) * 8, q4 = lane >> 4;
  const int m0 = (bid / tilesX) * BM, n0 = (bid % tilesX) * BN;

  // ---- B staging state ----
  const int bn = tid & (BN - 1);
  const int bkp0 = (tid / BN) * KPT;
  const float* Bbase = Bw + (size_t)(2 * bkp0) * ldb + n0 + bn;
  float fb[2 * KPT];

  // ---- A staging state (cast path) ----
  const float* Af = (const float*)Ap;
  const unsigned short* Abf = (const unsigned short*)Ap;
  const int arow = tid >> 1, akh = tid & 1;
  float fa[16];

  auto loadB = [&](int t) {
#pragma unroll
    for (int j = 0; j < 2 * KPT; ++j)
      fb[j] = Bbase[(size_t)(t * BK + j) * ldb];
  };
  auto writeB = [&](unsigned short* dB) {
    unsigned pk[KPT];
#pragma unroll
    for (int pj = 0; pj < KPT; ++pj)
      pk[pj] = (unsigned)f2bf(fb[2 * pj]) | ((unsigned)f2bf(fb[2 * pj + 1]) << 16);
#pragma unroll
    for (int c = 0; c < KPT / 4; ++c) {
      u32x4 u = {pk[4 * c], pk[4 * c + 1], pk[4 * c + 2], pk[4 * c + 3]};
      *(u32x4*)(dB + (size_t)bn * LDB + 2 * (bkp0 + 4 * c)) = u;
    }
  };
  auto loadA = [&](int t) {
    if constexpr (A_CAST) {
#pragma unroll
      for (int i = 0; i < 4; ++i) {
        float4 v = *(const float4*)(Af + (size_t)(m0 + arow) * KDIM + t * BK + akh * 16 + i * 4);
        fa[4 * i] = v.x; fa[4 * i + 1] = v.y; fa[4 * i + 2] = v.z; fa[4 * i + 3] = v.w;
      }
    }
  };
  auto writeA = [&](unsigned short* dA) {
    unsigned pk[8];
#pragma unroll
    for (int j = 0; j < 8; ++j)
      pk[j] = (unsigned)f2bf(fa[2 * j]) | ((unsigned)f2bf(fa[2 * j + 1]) << 16);
#pragma unroll
    for (int c = 0; c < 2; ++c) {
      u32x4 u = {pk[4 * c], pk[4 * c + 1], pk[4 * c + 2], pk[4 * c + 3]};
      *(u32x4*)(dA + (size_t)arow * LDA + akh * 16 + c * 8) = u;
    }
  };
  auto stageA_lds = [&](int t, unsigned short* dA) {
#pragma unroll
    for (int i = 0; i < BM / 64; ++i) {
      int c = i * 256 + tid, row = c >> 2, c8 = (c & 3) * 8;
      load16_to_lds(&Abf[(size_t)(m0 + row) * KDIM + t * BK + c8], dA + c * 8);
    }
  };

  // ---- prologue: tile 0 staged, tile 1 loads in flight ----
  loadB(0);
  if constexpr (A_CAST) loadA(0); else stageA_lds(0, lA);
  writeB(lB);
  if constexpr (A_CAST) writeA(lA);
  loadB(1);
  if constexpr (A_CAST) loadA(1);

  f32x4 acc[MT][NT] = {};
  for (int t = 0; t < nt; ++t) {
    const int cur = t & 1;
    unsigned short* cA = lA + cur * ASZ;
    unsigned short* cB = lB + cur * BSZ;
    unsigned short* nA = lA + (cur ^ 1) * ASZ;
    unsigned short* nB = lB + (cur ^ 1) * BSZ;
    __syncthreads();  // buf[cur] ds_writes visible; async A_lds drained
    s16x8 a[MT], b[NT];
#pragma unroll
    for (int mi = 0; mi < MT; ++mi)
      a[mi] = *(const s16x8*)&cA[(size_t)(wr * BM2 + mi * 16 + fm) * LDA + q8];
#pragma unroll
    for (int ni = 0; ni < NT; ++ni)
      b[ni] = *(const s16x8*)&cB[(size_t)(wc * BN2 + ni * 16 + fm) * LDB + q8];
    if (t + 1 < nt) {
      writeB(nB);
      if constexpr (A_CAST) writeA(nA); else stageA_lds(t + 1, nA);
    }
    if (t + 2 < nt) {
      loadB(t + 2);
      if constexpr (A_CAST) loadA(t + 2);
    }
#pragma unroll
    for (int mi = 0; mi < MT; ++mi)
#pragma unroll
      for (int ni = 0; ni < NT; ++ni)
        acc[mi][ni] = __builtin_amdgcn_mfma_f32_16x16x32_bf16(a[mi], b[ni], acc[mi][ni], 0, 0, 0);
  }
#pragma unroll
  for (int mi = 0; mi < MT; ++mi)
#pragma unroll
    for (int ni = 0; ni < NT; ++ni)
#pragma unroll
      for (int r = 0; r < 4; ++r) {
        int row = m0 + wr * BM2 + mi * 16 + q4 * 4 + r;
        int col = n0 + wc * BN2 + ni * 16 + fm;
        if constexpr (OUT16)
          ((unsigned short*)Cp)[(size_t)row * N + col] = f2bf(acc[mi][ni][r]);
        else
          ((float*)Cp)[(size_t)row * N + col] = acc[mi][ni][r];
      }
}

// qkv = x(f32) @ Wqkv(f32) -> bf16.  192 blocks (16x12 tiles of 128x128).
__global__ __launch_bounds__(256) void gemm1_kernel(const float* __restrict__ x,
                                                    const float* __restrict__ Wqkv,
                                                    unsigned short* __restrict__ Cc) {
  __shared__ __align__(16) unsigned short smem[2 * 128 * 40 + 2 * 128 * 40];
  gemm_body<128, 128, C_DIM, true, true>(x, Wqkv, Cc, QKV_LD, QKV_LD, 12,
                                         smem, smem + 2 * 128 * 40,
                                         threadIdx.x, blockIdx.x);
}
// out = Ybf(bf16) @ Wout(f32) -> f32.  256 blocks (32x8 tiles of 64x64).
__global__ __launch_bounds__(256) void gemm2_kernel(const unsigned short* __restrict__ Ybf,
                                                    const float* __restrict__ Wout,
                                                    float* __restrict__ Cc) {
  __shared__ __align__(16) unsigned short smem[2 * 64 * 32 + 2 * 64 * 40];
  gemm_body<64, 64, C_DIM, false, false>(Ybf, Wout, Cc, C_DIM, C_DIM, 8,
                                         smem, smem + 2 * 64 * 32,
                                         threadIdx.x, blockIdx.x);
}

// ---------------------------------------------------------------------------
// MFMA attention: 512 blocks (8 heads x 64 t-tiles of 32 slots).  R4 version:
// conflict-free V^T staging, wave-parallel softmax, T14 early V-gather.
// ---------------------------------------------------------------------------
__global__ __launch_bounds__(256) void attn_kernel(const unsigned short* __restrict__ qkvbf,
                                                   const int* __restrict__ perms,
                                                   unsigned short* __restrict__ Ybf) {
  __shared__ __align__(16) unsigned char smem[48768];
  int* ow            = (int*)smem;                           // [128]
  unsigned short* lQ = (unsigned short*)(smem + 512);        // [32][72]
  unsigned short* lK = (unsigned short*)(smem + 5120);       // [128][72]
  float* Sb          = (float*)(smem + 23552);               // [32][129]
  unsigned short* lP = (unsigned short*)(smem + 40064);      // [32][136]
  unsigned short* lVT= (unsigned short*)(smem + 5120);       // [64][136] overlays lK

  const int tid = threadIdx.x, bid = blockIdx.x;
  const int lane = tid & 63, w = tid >> 6;
  const int fm = lane & 15, q8 = (lane >> 4) * 8, q4 = lane >> 4;
  const int h = bid >> 6;
  const int t0 = (bid & 63) << 5;

  if (tid < 128) {
    int pi = t0 - 48 + tid;
    int idx = min(max(pi, 0), T_DIM - 1);
    ow[tid] = perms[h * T_DIM + idx];
  }
  __syncthreads();

#pragma unroll
  for (int it = 0; it < 4; ++it) {
    int c = it * 256 + tid;
    int row = c >> 3, k8 = c & 7;
    uint4 d = *(const uint4*)(qkvbf + (size_t)ow[row] * QKV_LD + C_DIM + h * 64 + k8 * 8);
    *(uint4*)(lK + row * 72 + k8 * 8) = d;
  }
  {
    int row = tid >> 3, k8 = tid & 7;
    uint4 d = *(const uint4*)(qkvbf + (size_t)ow[48 + row] * QKV_LD + h * 64 + k8 * 8);
    *(uint4*)(lQ + row * 72 + k8 * 8) = d;
  }

  // T14: issue V-gather loads NOW (into regs); they fly under QK^T below.
  uint4 va[2], vb[2];
#pragma unroll
  for (int it = 0; it < 2; ++it) {
    int c2 = it * 256 + tid;
    int r = c2 & 63, d0 = (c2 >> 6) * 8;
    va[it] = *(const uint4*)(qkvbf + (size_t)ow[2 * r]     * QKV_LD + 2 * C_DIM + h * 64 + d0);
    vb[it] = *(const uint4*)(qkvbf + (size_t)ow[2 * r + 1] * QKV_LD + 2 * C_DIM + h * 64 + d0);
  }
  __syncthreads();

  // S = Q·K^T via MFMA; wave w owns key-cols [w*32, w*32+32)
  {
    f32x4 accs[2][2] = {};
#pragma unroll
    for (int kt = 0; kt < 2; ++kt) {
      s16x8 aq[2];
#pragma unroll
      for (int mi = 0; mi < 2; ++mi)
        aq[mi] = *(const s16x8*)&lQ[(mi * 16 + fm) * 72 + kt * 32 + q8];
#pragma unroll
      for (int ni = 0; ni < 2; ++ni) {
        s16x8 bk = *(const s16x8*)&lK[(w * 32 + ni * 16 + fm) * 72 + kt * 32 + q8];
#pragma unroll
        for (int mi = 0; mi < 2; ++mi)
          accs[mi][ni] = __builtin_amdgcn_mfma_f32_16x16x32_bf16(aq[mi], bk, accs[mi][ni], 0, 0, 0);
      }
    }
#pragma unroll
    for (int mi = 0; mi < 2; ++mi)
#pragma unroll
      for (int ni = 0; ni < 2; ++ni)
#pragma unroll
        for (int r = 0; r < 4; ++r)
          Sb[(mi * 16 + q4 * 4 + r) * 129 + w * 32 + ni * 16 + fm] = accs[mi][ni][r] * 0.125f;
  }
  __syncthreads();

  // stage V^T [64 d][128 key] over lK from the pre-loaded regs
#pragma unroll
  for (int it = 0; it < 2; ++it) {
    int c2 = it * 256 + tid;
    int r = c2 & 63, d0 = (c2 >> 6) * 8;
    uint4 a4 = va[it], b4 = vb[it];
    *(unsigned*)(lVT + (d0 + 0) * 136 + 2 * r) = (a4.x & 0xffffu) | (b4.x << 16);
    *(unsigned*)(lVT + (d0 + 1) * 136 + 2 * r) = (a4.x >> 16) | (b4.x & 0xffff0000u);
    *(unsigned*)(lVT + (d0 + 2) * 136 + 2 * r) = (a4.y & 0xffffu) | (b4.y << 16);
    *(unsigned*)(lVT + (d0 + 3) * 136 + 2 * r) = (a4.y >> 16) | (b4.y & 0xffff0000u);
    *(unsigned*)(lVT + (d0 + 4) * 136 + 2 * r) = (a4.z & 0xffffu) | (b4.z << 16);
    *(unsigned*)(lVT + (d0 + 5) * 136 + 2 * r) = (a4.z >> 16) | (b4.z & 0xffff0000u);
    *(unsigned*)(lVT + (d0 + 6) * 136 + 2 * r) = (a4.w & 0xffffu) | (b4.w << 16);
    *(unsigned*)(lVT + (d0 + 7) * 136 + 2 * r) = (a4.w >> 16) | (b4.w & 0xffff0000u);
  }

  // softmax: wave w owns q-rows w*8..w*8+7; lane owns cols (lane, lane+64)
  for (int si = 0; si < 8; ++si) {
    const int s = w * 8 + si;
    const int p = ow[48 + s];
    const int c1 = lane + 64;
    const float v0 = Sb[s * 129 + lane];
    const float v1 = Sb[s * 129 + c1];
    const int pi0 = t0 - 48 + lane;
    const bool valid0 = (lane >= s) && (pi0 >= 0) && (pi0 < T_DIM) && (ow[lane] <= p);
    const bool valid1 = (lane <= s + 32) && (pi0 + 64 < T_DIM) && (ow[c1] <= p);
    float mx = fmaxf(valid0 ? v0 : -FLT_MAX, valid1 ? v1 : -FLT_MAX);
#pragma unroll
    for (int off = 32; off > 0; off >>= 1) mx = fmaxf(mx, __shfl_xor(mx, off, 64));
    const float e0 = valid0 ? __expf(v0 - mx) : 0.f;
    const float e1 = valid1 ? __expf(v1 - mx) : 0.f;
    float sum = e0 + e1;
#pragma unroll
    for (int off = 32; off > 0; off >>= 1) sum += __shfl_xor(sum, off, 64);
    const float inv = 1.f / sum;
    lP[s * 136 + lane] = valid0 ? f2bf(e0 * inv) : (unsigned short)0;
    lP[s * 136 + c1]   = valid1 ? f2bf(e1 * inv) : (unsigned short)0;
  }
  __syncthreads();

  // O = P·V^T via MFMA; wave (wr,wc): m-tile wr, n-tiles wc*2+{0,1}
  {
    const int wr = w >> 1, wc = w & 1;
    f32x4 acco[2] = {};
#pragma unroll
    for (int kt = 0; kt < 4; ++kt) {
      s16x8 ap = *(const s16x8*)&lP[(wr * 16 + fm) * 136 + kt * 32 + q8];
#pragma unroll
      for (int ni = 0; ni < 2; ++ni) {
        s16x8 bv = *(const s16x8*)&lVT[((wc * 2 + ni) * 16 + fm) * 136 + kt * 32 + q8];
        acco[ni] = __builtin_amdgcn_mfma_f32_16x16x32_bf16(ap, bv, acco[ni], 0, 0, 0);
      }
    }
#pragma unroll
    for (int ni = 0; ni < 2; ++ni)
#pragma unroll
      for (int r = 0; r < 4; ++r) {
        int q = wr * 16 + q4 * 4 + r;
        int d = (wc * 2 + ni) * 16 + fm;
        Ybf[(size_t)ow[48 + q] * C_DIM + h * 64 + d] = f2bf(acco[ni][r]);
      }
  }
}

// ---------------------------------------------------------------------------
extern "C" void kernel_launch(void* const* d_in, const int* in_sizes, int n_in,
                              void* d_out, int out_size, void* d_ws, size_t ws_size,
                              hipStream_t stream) {
  const float* x     = (const float*)d_in[0];
  const float* Wqkv  = (const float*)d_in[1];
  const float* Wout  = (const float*)d_in[2];
  const int*   perms = (const int*)d_in[3];
  float* out = (float*)d_out;
  unsigned short* ws = (unsigned short*)d_ws;

  unsigned short* qkvbf = ws;                    // [2048][1536]
  unsigned short* Ybf   = qkvbf + 3145728;       // [2048][512]

  gemm1_kernel<<<192, 256, 0, stream>>>(x, Wqkv, qkvbf);
  attn_kernel<<<NBLK, 256, 0, stream>>>(qkvbf, perms, Ybf);
  gemm2_kernel<<<256, 256, 0, stream>>>(Ybf, Wout, out);
}